// Round 3
// baseline (392.009 us; speedup 1.0000x reference)
//
#include <hip/hip_runtime.h>
#include <hip/hip_bf16.h>

typedef __bf16 bf16;
typedef __bf16 bf16x8 __attribute__((ext_vector_type(8)));
typedef float floatx4 __attribute__((ext_vector_type(4)));

#define MFMA16(a, b, c) __builtin_amdgcn_mfma_f32_16x16x32_bf16((a), (b), (c), 0, 0, 0)

__device__ inline void gload_lds16(const void* g, void* l) {
    __builtin_amdgcn_global_load_lds((__attribute__((address_space(1))) void*)g,
                                     (__attribute__((address_space(3))) void*)l, 16, 0, 0);
}

// ---------------------------------------------------------------------------
// Kernel 1: fold W into W2:  W2fT[i*64+l, p] = sum_j W2[p, i*64+j] * W[l, j]
// (= B^T operand for the main GEMM, bf16). Also b2f[i*64+l] = sum_j b2[i*64+j]W[l,j]
// (blockIdx.x == 32 handles b2f; written to d_out[0..4096), consumed by GEMM
// epilogue, later overwritten by the final kernel — stream-ordered).
// Same memory traffic as a plain transpose (64 MB read, 32 MB write) + tiny MFMA.
// ---------------------------------------------------------------------------
__global__ __launch_bounds__(256) void fold_w2(
    const float* __restrict__ W2,  // [4096,4096]
    const float* __restrict__ W,   // [64,64]
    const float* __restrict__ b2,  // [4096]
    bf16* __restrict__ W2fT,       // [4096,4096] (n=i*64+l, k=p)
    float* __restrict__ b2f)       // [4096]
{
    int t = threadIdx.x;
    int pt = blockIdx.x, i = blockIdx.y;

    if (pt == 32) {  // b2f rows for this i
        if (t < 64) {
            float acc = 0.f;
            const float* b2r = b2 + i * 64;
            const float* wr_ = W + t * 64;
#pragma unroll
            for (int j = 0; j < 64; j++) acc = fmaf(b2r[j], wr_[j], acc);
            b2f[i * 64 + t] = acc;
        }
        return;
    }

    __shared__ bf16 sW[64 * 72];
    __shared__ bf16 sA[128 * 72];
    __shared__ bf16 sT[64 * 136];
    int w = t >> 6, l = t & 63;
    int lm = l & 15, q8 = (l >> 4) * 8;
    int p0 = pt * 128;

    // W rows -> sW (B operand: B[n=l][k=j] = W[l,j], natural layout)
#pragma unroll
    for (int kk = 0; kk < 16; kk++) {
        int idx = t + 256 * kk;
        sW[(idx >> 6) * 72 + (idx & 63)] = (bf16)W[idx];
    }
    // A tile: rows p in [p0,p0+128), cols j=0..63 from W2[p, i*64+j]
    {
        const float* src = W2 + (size_t)p0 * 4096 + i * 64;
#pragma unroll
        for (int kk = 0; kk < 8; kk++) {
            int c = t + 256 * kk;
            int row = c >> 4, j4 = (c & 15) * 4;
            float4 v = *(const float4*)(src + (size_t)row * 4096 + j4);
            bf16 tmp[4] = {(bf16)v.x, (bf16)v.y, (bf16)v.z, (bf16)v.w};
            *(uint2*)(sA + row * 72 + j4) = *(const uint2*)tmp;
        }
    }
    __syncthreads();

    // C[p,l] = sum_j A[p,j] W[l,j]; wave w owns p-rows [w*32, w*32+32)
    floatx4 acc[2][4] = {};
#pragma unroll
    for (int kc = 0; kc < 2; kc++) {
        bf16x8 a0 = *(const bf16x8*)(sA + (w * 32 + lm) * 72 + kc * 32 + q8);
        bf16x8 a1 = *(const bf16x8*)(sA + (w * 32 + 16 + lm) * 72 + kc * 32 + q8);
#pragma unroll
        for (int jn = 0; jn < 4; jn++) {
            bf16x8 bf_ = *(const bf16x8*)(sW + (jn * 16 + lm) * 72 + kc * 32 + q8);
            acc[0][jn] = MFMA16(a0, bf_, acc[0][jn]);
            acc[1][jn] = MFMA16(a1, bf_, acc[1][jn]);
        }
    }
    // transpose in LDS: sT[l][p]
#pragma unroll
    for (int im = 0; im < 2; im++)
#pragma unroll
        for (int jn = 0; jn < 4; jn++) {
            int pr = w * 32 + im * 16 + (l >> 4) * 4;
            int lc = jn * 16 + lm;
            union { bf16 h4[4]; uint2 u; } pk;
#pragma unroll
            for (int r = 0; r < 4; r++) pk.h4[r] = (bf16)acc[im][jn][r];
            *(uint2*)(sT + lc * 136 + pr) = pk.u;
        }
    __syncthreads();
    // coalesced write: row n = i*64+l over p
#pragma unroll
    for (int kk = 0; kk < 4; kk++) {
        int c = t + 256 * kk;
        int row = c >> 4, off = (c & 15) * 8;
        uint4 v = *(const uint4*)(sT + row * 136 + off);
        *(uint4*)(W2fT + (size_t)(i * 64 + row) * 4096 + p0 + off) = v;
    }
}

// ---------------------------------------------------------------------------
// Kernel 2: h = silu(Y @ W1 + b1), bf16 out.  Y:[B,64] W1:[64,4096]
// ---------------------------------------------------------------------------
#define BB 32
__global__ __launch_bounds__(256) void mlp1_kernel(
    const float* __restrict__ Y, const float* __restrict__ W1,
    const float* __restrict__ b1, bf16* __restrict__ h)
{
    int n = blockIdx.x * 256 + threadIdx.x;
    int b0 = blockIdx.y * BB;
    float bias = b1[n];
    float acc[BB];
#pragma unroll
    for (int b = 0; b < BB; b++) acc[b] = bias;
    for (int k = 0; k < 64; k++) {
        float wv = W1[k * 4096 + n];
#pragma unroll
        for (int b = 0; b < BB; b++)
            acc[b] = fmaf(Y[(b0 + b) * 64 + k], wv, acc[b]);
    }
#pragma unroll
    for (int b = 0; b < BB; b++) {
        float v = acc[b];
        v = v / (1.f + __expf(-v));
        h[(size_t)(b0 + b) * 4096 + n] = (bf16)v;
    }
}

// ---------------------------------------------------------------------------
// Kernel 3: C = A @ BT^T + bias, 128x128 tile, BK=32, double-buffered,
// one barrier/iter. LDS chunk swizzle: slot s of row r holds k-chunk (s+r)&3
// (staging picks per-lane global k-chunk; fragment reads use slot (q2-r)&3).
// Breaks the 8-way bank conflict of unpadded 64B rows down to 4-way.
// ---------------------------------------------------------------------------
#define GT 128
#define GK 32
__global__ __launch_bounds__(256, 4) void gemm_bt_bias(
    const bf16* __restrict__ A, const bf16* __restrict__ BT,
    const float* __restrict__ bias, bf16* __restrict__ C,
    int M, int N, int K)
{
    __shared__ bf16 sA[2][GT * GK];
    __shared__ bf16 sB[2][GT * GK];
    int t = threadIdx.x, w = t >> 6, l = t & 63;

    int bid = blockIdx.x;
    int xcd = bid & 7, local = bid >> 3;
    int mt = xcd * 4 + (local & 3);
    int nt = local >> 2;
    int m0 = mt * GT, n0 = nt * GT;

    int lm = l & 15;
    int q2 = l >> 4;
    int soff = ((q2 - (l & 3)) & 3) * 8;  // swizzled slot offset (per-lane const)
    int wr = (w >> 1) * 64, wc = (w & 1) * 64;

    // staging: chunk c = w*64 + it*256 + l; row = c>>2; slot s = l&3;
    // fetch k-chunk (s + row)&3
    int rowA = (w * 64 + l) >> 2;
    int ko = (((l & 3) + rowA) & 3) * 8;
    const bf16* pa = A + (size_t)(m0 + rowA) * K + ko;
    const bf16* pb = BT + (size_t)(n0 + rowA) * K + ko;
    const int base0 = (w * 64) * 8, base1 = (w * 64 + 256) * 8;

    floatx4 acc[4][4] = {};

    auto issue = [&](int buf, const bf16* a, const bf16* b) {
        gload_lds16(a, &sA[buf][base0]);
        gload_lds16(a + (size_t)64 * K, &sA[buf][base1]);
        gload_lds16(b, &sB[buf][base0]);
        gload_lds16(b + (size_t)64 * K, &sB[buf][base1]);
    };

    const int KT = K / GK;
    issue(0, pa, pb);
    pa += GK; pb += GK;
    __syncthreads();

    for (int kt = 0; kt < KT; ++kt) {
        int cur = kt & 1;
        if (kt + 1 < KT) {
            issue(cur ^ 1, pa, pb);
            pa += GK; pb += GK;
        }
        const bf16* LA = sA[cur];
        const bf16* LB = sB[cur];
        bf16x8 af[4], bfr[4];
#pragma unroll
        for (int i = 0; i < 4; i++)
            af[i] = *(const bf16x8*)(LA + (wr + i * 16 + lm) * GK + soff);
#pragma unroll
        for (int j = 0; j < 4; j++)
            bfr[j] = *(const bf16x8*)(LB + (wc + j * 16 + lm) * GK + soff);
#pragma unroll
        for (int i = 0; i < 4; i++)
#pragma unroll
            for (int j = 0; j < 4; j++)
                acc[i][j] = MFMA16(af[i], bfr[j], acc[i][j]);
        __syncthreads();
    }

#pragma unroll
    for (int i = 0; i < 4; i++) {
        int r0 = m0 + wr + i * 16 + (l >> 4) * 4;
#pragma unroll
        for (int j = 0; j < 4; j++) {
            int cc = n0 + wc + j * 16 + lm;
            float bb = bias[cc];
#pragma unroll
            for (int r = 0; r < 4; r++)
                C[(size_t)(r0 + r) * N + cc] = (bf16)(acc[i][j][r] + bb);
        }
    }
}

// ---------------------------------------------------------------------------
// Kernel 4: out = F X F^T (X symmetric, F = reshape(h W2f + b2f) precomputed).
//   S2: T = mm(sF, sX)  (= F X)     -> sT
//   S3: out = mm(sT, sF) (= T F^T)  -> global fp32
// 3 LDS buffers (27.6 KB) -> 5 blocks/CU. Zero-fill fused with diag-inject,
// disjoint from x-fill regions -> single barrier before S2.
// ---------------------------------------------------------------------------
#define ST 72
__global__ __launch_bounds__(256) void batched_congruence(
    const float* __restrict__ x,   // [B,48,48]
    const bf16* __restrict__ F,    // [B,4096]
    float* __restrict__ out)       // [B,4096]
{
    __shared__ bf16 sX[64 * ST], sF[64 * ST], sT[64 * ST];
    int t = threadIdx.x, w = t >> 6, l = t & 63;
    int b = blockIdx.x;
    int lm = l & 15, q8 = (l >> 4) * 8;
    int r0 = (w >> 1) * 32, c0 = (w & 1) * 32;

    // issue x loads early (regs)
    const float4* xb = (const float4*)(x + (size_t)b * 2304);
    float4 v0 = xb[t];
    float4 v1 = xb[t + 256];
    float4 v2 = (t < 64) ? xb[t + 512] : make_float4(0.f, 0.f, 0.f, 0.f);

    // F rows
    {
        const uint4* gf = (const uint4*)(F + (size_t)b * 4096);
#pragma unroll
        for (int kk = 0; kk < 2; kk++) {
            int c = t + 256 * kk;
            *(uint4*)(sF + (c >> 3) * ST + (c & 7) * 8) = gf[c];
        }
    }
    // zero X border + inject padded-diagonal ones (disjoint from x-fill):
    // region A: rows 0-47, dwords 24-31 (cols 48-63): 384 dwords
    // region B: rows 48-63, dwords 0-31: 512 dwords (diag one where col==row)
    {
        unsigned* sx32 = (unsigned*)sX;
#pragma unroll
        for (int kk = 0; kk < 4; kk++) {
            int idx = t + 256 * kk;
            if (idx < 384) {
                int r = idx >> 3, d = 24 + (idx & 7);
                sx32[r * 36 + d] = 0u;
            } else if (idx < 896) {
                int k2 = idx - 384;
                int r = 48 + (k2 >> 5), d = k2 & 31;
                unsigned val = 0u;
                if (d == (r >> 1)) val = (r & 1) ? 0x3F800000u : 0x00003F80u;
                sx32[r * 36 + d] = val;
            }
        }
    }
    // x fill: rows 0-47, cols 0-47 (dwords 0-23)
    {
        int c = t;
        bf16 p4[4];
        p4[0] = (bf16)v0.x; p4[1] = (bf16)v0.y; p4[2] = (bf16)v0.z; p4[3] = (bf16)v0.w;
        *(uint2*)(sX + (c / 12) * ST + (c % 12) * 4) = *(const uint2*)p4;
        c = t + 256;
        p4[0] = (bf16)v1.x; p4[1] = (bf16)v1.y; p4[2] = (bf16)v1.z; p4[3] = (bf16)v1.w;
        *(uint2*)(sX + (c / 12) * ST + (c % 12) * 4) = *(const uint2*)p4;
        if (t < 64) {
            c = t + 512;
            p4[0] = (bf16)v2.x; p4[1] = (bf16)v2.y; p4[2] = (bf16)v2.z; p4[3] = (bf16)v2.w;
            *(uint2*)(sX + (c / 12) * ST + (c % 12) * 4) = *(const uint2*)p4;
        }
    }
    __syncthreads();

    auto mm = [&](const bf16* PA, const bf16* PB, floatx4 acc[2][2]) {
#pragma unroll
        for (int kc = 0; kc < 2; kc++) {
            bf16x8 a0 = *(const bf16x8*)(PA + (r0 + lm) * ST + kc * 32 + q8);
            bf16x8 a1 = *(const bf16x8*)(PA + (r0 + 16 + lm) * ST + kc * 32 + q8);
            bf16x8 b0 = *(const bf16x8*)(PB + (c0 + lm) * ST + kc * 32 + q8);
            bf16x8 b1 = *(const bf16x8*)(PB + (c0 + 16 + lm) * ST + kc * 32 + q8);
            acc[0][0] = MFMA16(a0, b0, acc[0][0]);
            acc[0][1] = MFMA16(a0, b1, acc[0][1]);
            acc[1][0] = MFMA16(a1, b0, acc[1][0]);
            acc[1][1] = MFMA16(a1, b1, acc[1][1]);
        }
    };

    floatx4 z = {0.f, 0.f, 0.f, 0.f};
    {   // S2: T = F . X^T (= F X, X symmetric)
        floatx4 acc[2][2] = {{z, z}, {z, z}};
        mm(sF, sX, acc);
#pragma unroll
        for (int i = 0; i < 2; i++)
#pragma unroll
            for (int j = 0; j < 2; j++) {
                int R = r0 + i * 16 + (l >> 4) * 4;
                int Cc = c0 + j * 16 + lm;
#pragma unroll
                for (int r = 0; r < 4; r++)
                    sT[(R + r) * ST + Cc] = (bf16)acc[i][j][r];
            }
    }
    __syncthreads();
    {   // S3: out = T . F^T
        floatx4 acc[2][2] = {{z, z}, {z, z}};
        mm(sT, sF, acc);
        float* ob = out + (size_t)b * 4096;
#pragma unroll
        for (int i = 0; i < 2; i++)
#pragma unroll
            for (int j = 0; j < 2; j++) {
                int R = r0 + i * 16 + (l >> 4) * 4;
                int Cc = c0 + j * 16 + lm;
#pragma unroll
                for (int r = 0; r < 4; r++)
                    ob[(size_t)(R + r) * 64 + Cc] = acc[i][j][r];
            }
    }
}

// ---------------------------------------------------------------------------
extern "C" void kernel_launch(void* const* d_in, const int* in_sizes, int n_in,
                              void* d_out, int out_size, void* d_ws, size_t ws_size,
                              hipStream_t stream) {
    const float* x  = (const float*)d_in[0];
    const float* Y  = (const float*)d_in[2];
    const float* W  = (const float*)d_in[3];
    const float* W1 = (const float*)d_in[4];
    const float* b1 = (const float*)d_in[5];
    const float* W2 = (const float*)d_in[6];
    const float* b2 = (const float*)d_in[7];
    float* out = (float*)d_out;

    const size_t NN = (size_t)4096 * 4096;
    bf16* h    = (bf16*)d_ws;
    bf16* W2fT = h + NN;
    bf16* emb  = W2fT + NN;      // holds F flattened per sample
    float* b2f = (float*)d_out;  // stashed in d_out, consumed by GEMM, then overwritten

    fold_w2<<<dim3(33, 64), 256, 0, stream>>>(W2, W, b2, W2fT, b2f);
    mlp1_kernel<<<dim3(16, 128), 256, 0, stream>>>(Y, W1, b1, h);
    gemm_bt_bias<<<1024, 256, 0, stream>>>(h, W2fT, b2f, emb, 4096, 4096, 4096);
    batched_congruence<<<4096, 256, 0, stream>>>(x, emb, out);
}

// Round 4
// 332.155 us; speedup vs baseline: 1.1802x; 1.1802x over previous
//
#include <hip/hip_runtime.h>
#include <hip/hip_bf16.h>

typedef __bf16 bf16;
typedef __bf16 bf16x8 __attribute__((ext_vector_type(8)));
typedef float floatx4 __attribute__((ext_vector_type(4)));

#define MFMA16(a, b, c) __builtin_amdgcn_mfma_f32_16x16x32_bf16((a), (b), (c), 0, 0, 0)

__device__ inline void gload_lds16(const void* g, void* l) {
    __builtin_amdgcn_global_load_lds((__attribute__((address_space(1))) void*)g,
                                     (__attribute__((address_space(3))) void*)l, 16, 0, 0);
}

// ---------------------------------------------------------------------------
// Kernel 1 (fused prep): three roles by blockIdx.x
//   [0,2048)     fold_w2:  W2fT[i*64+l, p] = sum_j W2[p,i*64+j] W[l,j]  (bf16)
//   [2048,2112)  b2f:      b2f[i*64+l]     = sum_j b2[i*64+j]   W[l,j]
//   [2112,3136)  mlp1:     h = silu(Y @ W1 + b1)  via MFMA (K=64), bf16 out
// Shared-memory union: fold needs 44 KB, mlp 36 KB -> 45056 B static.
// ---------------------------------------------------------------------------
__global__ __launch_bounds__(256) void prep_fused(
    const float* __restrict__ W2,  // [4096,4096]
    const float* __restrict__ W,   // [64,64]
    const float* __restrict__ b2,  // [4096]
    const float* __restrict__ Y,   // [4096,64]
    const float* __restrict__ W1,  // [64,4096]
    const float* __restrict__ b1,  // [4096]
    bf16* __restrict__ W2fT,       // [4096,4096] (n, p)
    float* __restrict__ b2f,       // [4096]
    bf16* __restrict__ h)          // [4096,4096]
{
    __shared__ __align__(16) char smem[45056];
    int t = threadIdx.x, bid = blockIdx.x;
    int w = t >> 6, l = t & 63;
    int lm = l & 15, q2 = l >> 4, q8 = q2 * 8;

    if (bid < 2048) {
        // ---- fold_w2 ----
        int pt = bid & 31, i = bid >> 5;
        bf16* sW = (bf16*)smem;          // 64*72
        bf16* sA = sW + 64 * 72;         // 128*72
        bf16* sT = sA + 128 * 72;        // 64*136
        int p0 = pt * 128;

#pragma unroll
        for (int kk = 0; kk < 16; kk++) {
            int idx = t + 256 * kk;
            sW[(idx >> 6) * 72 + (idx & 63)] = (bf16)W[idx];
        }
        {
            const float* src = W2 + (size_t)p0 * 4096 + i * 64;
#pragma unroll
            for (int kk = 0; kk < 8; kk++) {
                int c = t + 256 * kk;
                int row = c >> 4, j4 = (c & 15) * 4;
                float4 v = *(const float4*)(src + (size_t)row * 4096 + j4);
                bf16 tmp[4] = {(bf16)v.x, (bf16)v.y, (bf16)v.z, (bf16)v.w};
                *(uint2*)(sA + row * 72 + j4) = *(const uint2*)tmp;
            }
        }
        __syncthreads();

        floatx4 acc[2][4] = {};
#pragma unroll
        for (int kc = 0; kc < 2; kc++) {
            bf16x8 a0 = *(const bf16x8*)(sA + (w * 32 + lm) * 72 + kc * 32 + q8);
            bf16x8 a1 = *(const bf16x8*)(sA + (w * 32 + 16 + lm) * 72 + kc * 32 + q8);
#pragma unroll
            for (int jn = 0; jn < 4; jn++) {
                bf16x8 bf_ = *(const bf16x8*)(sW + (jn * 16 + lm) * 72 + kc * 32 + q8);
                acc[0][jn] = MFMA16(a0, bf_, acc[0][jn]);
                acc[1][jn] = MFMA16(a1, bf_, acc[1][jn]);
            }
        }
#pragma unroll
        for (int im = 0; im < 2; im++)
#pragma unroll
            for (int jn = 0; jn < 4; jn++) {
                int pr = w * 32 + im * 16 + q2 * 4;
                int lc = jn * 16 + lm;
                union { bf16 h4[4]; uint2 u; } pk;
#pragma unroll
                for (int r = 0; r < 4; r++) pk.h4[r] = (bf16)acc[im][jn][r];
                *(uint2*)(sT + lc * 136 + pr) = pk.u;
            }
        __syncthreads();
#pragma unroll
        for (int kk = 0; kk < 4; kk++) {
            int c = t + 256 * kk;
            int row = c >> 4, off = (c & 15) * 8;
            uint4 v = *(const uint4*)(sT + row * 136 + off);
            *(uint4*)(W2fT + (size_t)(i * 64 + row) * 4096 + p0 + off) = v;
        }
        return;
    }

    if (bid < 2112) {
        // ---- b2f ----
        int i = bid - 2048;
        if (t < 64) {
            float acc = 0.f;
            const float* b2r = b2 + i * 64;
            const float* wr_ = W + t * 64;
#pragma unroll
            for (int j = 0; j < 64; j++) acc = fmaf(b2r[j], wr_[j], acc);
            b2f[i * 64 + t] = acc;
        }
        return;
    }

    // ---- mlp1 via MFMA: h[m,n] = silu(sum_k Y[m,k] W1[k,n] + b1[n]) ----
    {
        int q = bid - 2112;
        int m0 = (q >> 5) * 128, n0 = (q & 31) * 128;
        bf16* sY = (bf16*)smem;          // 128*72  (Y[m,k])
        bf16* sWT = sY + 128 * 72;       // 128*72  (W1T[n,k])

        // stage Y rows
#pragma unroll
        for (int kk = 0; kk < 8; kk++) {
            int c = t + 256 * kk;
            int row = c >> 4, c4 = (c & 15) * 4;
            float4 v = *(const float4*)(Y + (size_t)(m0 + row) * 64 + c4);
            bf16 tmp[4] = {(bf16)v.x, (bf16)v.y, (bf16)v.z, (bf16)v.w};
            *(uint2*)(sY + row * 72 + c4) = *(const uint2*)tmp;
        }
        // stage W1T (transpose scatter)
#pragma unroll
        for (int kk = 0; kk < 8; kk++) {
            int c = t + 256 * kk;
            int k = c >> 5, j4 = (c & 31) * 4;
            float4 v = *(const float4*)(W1 + (size_t)k * 4096 + n0 + j4);
            sWT[(j4 + 0) * 72 + k] = (bf16)v.x;
            sWT[(j4 + 1) * 72 + k] = (bf16)v.y;
            sWT[(j4 + 2) * 72 + k] = (bf16)v.z;
            sWT[(j4 + 3) * 72 + k] = (bf16)v.w;
        }
        __syncthreads();

        // D[n,m] = sum_k W1T[n,k] Y[m,k]  (transposed product so h-stores are
        // contiguous uint2: per-lane 4 consecutive n at fixed m)
        int wn = (w & 1) * 64, wm = (w >> 1) * 64;
        floatx4 acc[4][4] = {};
#pragma unroll
        for (int kc = 0; kc < 2; kc++) {
            bf16x8 af[4], bfr[4];
#pragma unroll
            for (int i = 0; i < 4; i++)
                af[i] = *(const bf16x8*)(sWT + (wn + i * 16 + lm) * 72 + kc * 32 + q8);
#pragma unroll
            for (int j = 0; j < 4; j++)
                bfr[j] = *(const bf16x8*)(sY + (wm + j * 16 + lm) * 72 + kc * 32 + q8);
#pragma unroll
            for (int i = 0; i < 4; i++)
#pragma unroll
                for (int j = 0; j < 4; j++)
                    acc[i][j] = MFMA16(af[i], bfr[j], acc[i][j]);
        }
        // epilogue: silu + bias, store uint2 (4 consecutive n)
#pragma unroll
        for (int i = 0; i < 4; i++) {
            int nb = n0 + wn + i * 16 + q2 * 4;
            float4 bv = *(const float4*)(b1 + nb);
            float bb[4] = {bv.x, bv.y, bv.z, bv.w};
#pragma unroll
            for (int j = 0; j < 4; j++) {
                int m = m0 + wm + j * 16 + lm;
                union { bf16 h4[4]; uint2 u; } pk;
#pragma unroll
                for (int r = 0; r < 4; r++) {
                    float v = acc[i][j][r] + bb[r];
                    v = v / (1.f + __expf(-v));
                    pk.h4[r] = (bf16)v;
                }
                *(uint2*)(h + (size_t)m * 4096 + nb) = pk.u;
            }
        }
    }
}

// ---------------------------------------------------------------------------
// Kernel 3: C = A @ BT^T + bias, 128x128 tile, BK=32, double-buffered,
// one barrier/iter (frozen from R3; chunk swizzle kept, neutral).
// ---------------------------------------------------------------------------
#define GT 128
#define GK 32
__global__ __launch_bounds__(256, 4) void gemm_bt_bias(
    const bf16* __restrict__ A, const bf16* __restrict__ BT,
    const float* __restrict__ bias, bf16* __restrict__ C,
    int M, int N, int K)
{
    __shared__ bf16 sA[2][GT * GK];
    __shared__ bf16 sB[2][GT * GK];
    int t = threadIdx.x, w = t >> 6, l = t & 63;

    int bid = blockIdx.x;
    int xcd = bid & 7, local = bid >> 3;
    int mt = xcd * 4 + (local & 3);
    int nt = local >> 2;
    int m0 = mt * GT, n0 = nt * GT;

    int lm = l & 15;
    int q2 = l >> 4;
    int soff = ((q2 - (l & 3)) & 3) * 8;
    int wr = (w >> 1) * 64, wc = (w & 1) * 64;

    int rowA = (w * 64 + l) >> 2;
    int ko = (((l & 3) + rowA) & 3) * 8;
    const bf16* pa = A + (size_t)(m0 + rowA) * K + ko;
    const bf16* pb = BT + (size_t)(n0 + rowA) * K + ko;
    const int base0 = (w * 64) * 8, base1 = (w * 64 + 256) * 8;

    floatx4 acc[4][4] = {};

    auto issue = [&](int buf, const bf16* a, const bf16* b) {
        gload_lds16(a, &sA[buf][base0]);
        gload_lds16(a + (size_t)64 * K, &sA[buf][base1]);
        gload_lds16(b, &sB[buf][base0]);
        gload_lds16(b + (size_t)64 * K, &sB[buf][base1]);
    };

    const int KT = K / GK;
    issue(0, pa, pb);
    pa += GK; pb += GK;
    __syncthreads();

    for (int kt = 0; kt < KT; ++kt) {
        int cur = kt & 1;
        if (kt + 1 < KT) {
            issue(cur ^ 1, pa, pb);
            pa += GK; pb += GK;
        }
        const bf16* LA = sA[cur];
        const bf16* LB = sB[cur];
        bf16x8 af[4], bfr[4];
#pragma unroll
        for (int i = 0; i < 4; i++)
            af[i] = *(const bf16x8*)(LA + (wr + i * 16 + lm) * GK + soff);
#pragma unroll
        for (int j = 0; j < 4; j++)
            bfr[j] = *(const bf16x8*)(LB + (wc + j * 16 + lm) * GK + soff);
#pragma unroll
        for (int i = 0; i < 4; i++)
#pragma unroll
            for (int j = 0; j < 4; j++)
                acc[i][j] = MFMA16(af[i], bfr[j], acc[i][j]);
        __syncthreads();
    }

#pragma unroll
    for (int i = 0; i < 4; i++) {
        int r0 = m0 + wr + i * 16 + (l >> 4) * 4;
#pragma unroll
        for (int j = 0; j < 4; j++) {
            int cc = n0 + wc + j * 16 + lm;
            float bb = bias[cc];
#pragma unroll
            for (int r = 0; r < 4; r++)
                C[(size_t)(r0 + r) * N + cc] = (bf16)(acc[i][j][r] + bb);
        }
    }
}

// ---------------------------------------------------------------------------
// Kernel 4: out = F X F^T (X symmetric).
//   S2: Q = mm(sX, sF) = X F^T = T^T; store TRANSPOSED (uint2, contiguous)
//       -> sT holds T = F X row-major
//   S3: out = mm(sT, sF) = T F^T -> global fp32
// ---------------------------------------------------------------------------
#define ST 72
__global__ __launch_bounds__(256) void batched_congruence(
    const float* __restrict__ x,   // [B,48,48]
    const bf16* __restrict__ F,    // [B,4096]
    float* __restrict__ out)       // [B,4096]
{
    __shared__ bf16 sX[64 * ST], sF[64 * ST], sT[64 * ST];
    int t = threadIdx.x, w = t >> 6, l = t & 63;
    int b = blockIdx.x;
    int lm = l & 15, q2 = l >> 4, q8 = q2 * 8;
    int r0 = (w >> 1) * 32, c0 = (w & 1) * 32;

    const float4* xb = (const float4*)(x + (size_t)b * 2304);
    float4 v0 = xb[t];
    float4 v1 = xb[t + 256];
    float4 v2 = (t < 64) ? xb[t + 512] : make_float4(0.f, 0.f, 0.f, 0.f);

    {
        const uint4* gf = (const uint4*)(F + (size_t)b * 4096);
#pragma unroll
        for (int kk = 0; kk < 2; kk++) {
            int c = t + 256 * kk;
            *(uint4*)(sF + (c >> 3) * ST + (c & 7) * 8) = gf[c];
        }
    }
    // zero X border + padded-diagonal ones (disjoint from x-fill)
    {
        unsigned* sx32 = (unsigned*)sX;
#pragma unroll
        for (int kk = 0; kk < 4; kk++) {
            int idx = t + 256 * kk;
            if (idx < 384) {
                int r = idx >> 3, d = 24 + (idx & 7);
                sx32[r * 36 + d] = 0u;
            } else if (idx < 896) {
                int k2 = idx - 384;
                int r = 48 + (k2 >> 5), d = k2 & 31;
                unsigned val = 0u;
                if (d == (r >> 1)) val = (r & 1) ? 0x3F800000u : 0x00003F80u;
                sx32[r * 36 + d] = val;
            }
        }
    }
    // x fill: rows 0-47, cols 0-47
    {
        int c = t;
        bf16 p4[4];
        p4[0] = (bf16)v0.x; p4[1] = (bf16)v0.y; p4[2] = (bf16)v0.z; p4[3] = (bf16)v0.w;
        *(uint2*)(sX + (c / 12) * ST + (c % 12) * 4) = *(const uint2*)p4;
        c = t + 256;
        p4[0] = (bf16)v1.x; p4[1] = (bf16)v1.y; p4[2] = (bf16)v1.z; p4[3] = (bf16)v1.w;
        *(uint2*)(sX + (c / 12) * ST + (c % 12) * 4) = *(const uint2*)p4;
        if (t < 64) {
            c = t + 512;
            p4[0] = (bf16)v2.x; p4[1] = (bf16)v2.y; p4[2] = (bf16)v2.z; p4[3] = (bf16)v2.w;
            *(uint2*)(sX + (c / 12) * ST + (c % 12) * 4) = *(const uint2*)p4;
        }
    }
    __syncthreads();

    auto mm = [&](const bf16* PA, const bf16* PB, floatx4 acc[2][2]) {
#pragma unroll
        for (int kc = 0; kc < 2; kc++) {
            bf16x8 a0 = *(const bf16x8*)(PA + (r0 + lm) * ST + kc * 32 + q8);
            bf16x8 a1 = *(const bf16x8*)(PA + (r0 + 16 + lm) * ST + kc * 32 + q8);
            bf16x8 b0 = *(const bf16x8*)(PB + (c0 + lm) * ST + kc * 32 + q8);
            bf16x8 b1 = *(const bf16x8*)(PB + (c0 + 16 + lm) * ST + kc * 32 + q8);
            acc[0][0] = MFMA16(a0, b0, acc[0][0]);
            acc[0][1] = MFMA16(a0, b1, acc[0][1]);
            acc[1][0] = MFMA16(a1, b0, acc[1][0]);
            acc[1][1] = MFMA16(a1, b1, acc[1][1]);
        }
    };

    floatx4 z = {0.f, 0.f, 0.f, 0.f};
    {   // S2: Q = X . F^T (row r from X, col c from F); Q = T^T.
        // Transposed store: sT[c][r..r+3] <- acc => sT = T row-major.
        floatx4 acc[2][2] = {{z, z}, {z, z}};
        mm(sX, sF, acc);
#pragma unroll
        for (int i = 0; i < 2; i++)
#pragma unroll
            for (int j = 0; j < 2; j++) {
                int R = r0 + i * 16 + q2 * 4;
                int Cc = c0 + j * 16 + lm;
                union { bf16 h4[4]; uint2 u; } pk;
#pragma unroll
                for (int r = 0; r < 4; r++) pk.h4[r] = (bf16)acc[i][j][r];
                *(uint2*)(sT + Cc * ST + R) = pk.u;
            }
    }
    __syncthreads();
    {   // S3: out = T . F^T
        floatx4 acc[2][2] = {{z, z}, {z, z}};
        mm(sT, sF, acc);
        float* ob = out + (size_t)b * 4096;
#pragma unroll
        for (int i = 0; i < 2; i++)
#pragma unroll
            for (int j = 0; j < 2; j++) {
                int R = r0 + i * 16 + q2 * 4;
                int Cc = c0 + j * 16 + lm;
#pragma unroll
                for (int r = 0; r < 4; r++)
                    out[(size_t)b * 4096 + (size_t)(R + r) * 64 + Cc] = acc[i][j][r];
            }
        (void)ob;
    }
}

// ---------------------------------------------------------------------------
extern "C" void kernel_launch(void* const* d_in, const int* in_sizes, int n_in,
                              void* d_out, int out_size, void* d_ws, size_t ws_size,
                              hipStream_t stream) {
    const float* x  = (const float*)d_in[0];
    const float* Y  = (const float*)d_in[2];
    const float* W  = (const float*)d_in[3];
    const float* W1 = (const float*)d_in[4];
    const float* b1 = (const float*)d_in[5];
    const float* W2 = (const float*)d_in[6];
    const float* b2 = (const float*)d_in[7];
    float* out = (float*)d_out;

    const size_t NN = (size_t)4096 * 4096;
    bf16* h    = (bf16*)d_ws;
    bf16* W2fT = h + NN;
    bf16* emb  = W2fT + NN;
    float* b2f = (float*)d_out;  // stashed in d_out; consumed by GEMM, then overwritten

    prep_fused<<<3136, 256, 0, stream>>>(W2, W, b2, Y, W1, b1, W2fT, b2f, h);
    gemm_bt_bias<<<1024, 256, 0, stream>>>(h, W2fT, b2f, emb, 4096, 4096, 4096);
    batched_congruence<<<4096, 256, 0, stream>>>(x, emb, out);
}